// Round 7
// baseline (23164.491 us; speedup 1.0000x reference)
//
#include <hip/hip_runtime.h>

typedef unsigned short u16;
typedef unsigned int u32;
typedef __attribute__((ext_vector_type(4))) float f32x4;
typedef __attribute__((ext_vector_type(8))) __bf16 bf16x8;
typedef __attribute__((ext_vector_type(4))) u16 u16x4;

#define TSEQ 512
#define BATCH 64
#define HDIM 256
#define KD   512          // compensated K: [Whi | Wlo]
#define GDIM 1024
#define EDIM 300
#define ELDA 304
#define TC   128          // time chunk
#define NC   4

__device__ __forceinline__ float b2f(u16 u){
  union { unsigned int i; float f; } v; v.i = ((unsigned int)u) << 16; return v.f;
}
__device__ __forceinline__ u16 f2b(float f){
  union { float f; unsigned int i; } v; v.f = f;
  unsigned int x = v.i;
  unsigned int r = (x + 0x7fffu + ((x >> 16) & 1u)) >> 16;
  return (u16)r;
}
__device__ __forceinline__ u16 f2h16(float f){
  _Float16 h = (_Float16)f; u16 u; __builtin_memcpy(&u, &h, 2); return u;
}
__device__ __forceinline__ float h162f(u16 u){
  _Float16 h; __builtin_memcpy(&h, &u, 2); return (float)h;
}
__device__ __forceinline__ float sigm(float x){
  return __builtin_amdgcn_rcpf(1.f + __expf(-x));
}
__device__ __forceinline__ float tanh_(float x){
  float e = __expf(2.f * x);
  return 1.f - 2.f * __builtin_amdgcn_rcpf(e + 1.f);
}
__device__ __forceinline__ f32x4 mfma16(bf16x8 a, bf16x8 b, f32x4 c){
  return __builtin_amdgcn_mfma_f32_16x16x32_bf16(a, b, c, 0, 0, 0);
}

// ---------------- Wih convert (fp32 -> bf16), 4 segments ----------------
struct Cvt7 {
  const float* src[4];
  u16* dst[4];
  int cum[5];
};
__global__ void k7_cvt(Cvt7 a){
  int g = blockIdx.x * 256 + threadIdx.x;
  if (g >= a.cum[4]) return;
  int s = 0;
#pragma unroll
  for (int i = 1; i < 4; ++i) if (g >= a.cum[i]) s = i;
  int off = g - a.cum[s];
  f32x4 v = *(const f32x4*)(a.src[s] + (size_t)off * 4);
  u16x4 o = { f2b(v[0]), f2b(v[1]), f2b(v[2]), f2b(v[3]) };
  *(u16x4*)(a.dst[s] + (size_t)off * 4) = o;
}

// ---------------- Whh convert: compensated hi|lo, transposed + swizzled chunks --------
// dst layout: [mat 4][kc 16][w 8][s 8][512 elems]  (1KB chunks, lane-linear staging order)
// chunk byte b (16B unit sub=b/16): l15 = sub>>2, q = sub&3, lq = q ^ ((l15>>2)&3)
// stores W[row = ((s>>1)*16 + 2w + (s&1))*16 + l15][k = kc*32 + lq*8 .. +8]
// k<256 -> hi plane of W[row][k];  k>=256 -> bf16 residual (lo plane) of W[row][k-256]
struct CvtW7 { const float* src[4]; u16* dst; };
__global__ void k7_cvtw(CvtW7 a){
  int g = blockIdx.x * 256 + threadIdx.x;   // 4 * 65536 sixteen-byte units
  int mat = g >> 16;
  int rem = g & 65535;
  int chunk = rem >> 6;        // [kc][w][s]
  int sub   = rem & 63;
  int kc = chunk >> 6, w = (chunk >> 3) & 7, s = chunk & 7;
  int l15 = sub >> 2, q = sub & 3;
  int lq = q ^ ((l15 >> 2) & 3);
  int row = ((s >> 1) * 16 + 2 * w + (s & 1)) * 16 + l15;
  int kk = kc * 32 + lq * 8;
  const float* srow = a.src[mat] + (size_t)row * HDIM;
  u16 o[8];
  if (kk < 256){
    f32x4 v0 = *(const f32x4*)(srow + kk);
    f32x4 v1 = *(const f32x4*)(srow + kk + 4);
#pragma unroll
    for (int e = 0; e < 4; ++e){ o[e] = f2b(v0[e]); o[4 + e] = f2b(v1[e]); }
  } else {
    int k2 = kk - 256;
    f32x4 v0 = *(const f32x4*)(srow + k2);
    f32x4 v1 = *(const f32x4*)(srow + k2 + 4);
#pragma unroll
    for (int e = 0; e < 4; ++e){
      u16 h0 = f2b(v0[e]); o[e]     = f2b(v0[e] - b2f(h0));
      u16 h1 = f2b(v1[e]); o[4 + e] = f2b(v1[e] - b2f(h1));
    }
  }
  u16* d = a.dst + (size_t)mat * 524288 + (size_t)chunk * 512 + sub * 8;
  *(u16x4*)d = (u16x4){o[0], o[1], o[2], o[3]};
  *(u16x4*)(d + 4) = (u16x4){o[4], o[5], o[6], o[7]};
}

// ---------------- bias sums ----------------
struct Bias7 { const float* a[4]; const float* b[4]; float* d[4]; };
__global__ void k7_bias(Bias7 z){
  int k = blockIdx.x, i = threadIdx.x;
  z.d[k][i] = z.a[k][i] + z.b[k][i];
}

// ---------------- embedding gather + bf16 cast ----------------
__global__ void k7_embed(const int* __restrict__ text, const float* __restrict__ emb,
                         u16* __restrict__ xbf){
  int row = blockIdx.x;
  int t = threadIdx.x;
  if (t >= 75) return;
  int tok = text[row];
  f32x4 v = *(const f32x4*)(emb + (size_t)tok * EDIM + t * 4);
  u16x4 o = { f2b(v[0]), f2b(v[1]), f2b(v[2]), f2b(v[3]) };
  *(u16x4*)(xbf + (size_t)row * ELDA + t * 4) = o;
}

// ---------------- chunked MFMA GEMM: xg_chunk = A @ W^T + bias (fp16 out) ----------------
struct Gemm7 {
  const u16* A; long lda; int K, KT;
  const u16* W0; const u16* W1; long ldw;
  const float* bias0; const float* bias1;
  u16* out;              // [2][64][TC][1024] fp16
  int tb0, tb1;
};
__global__ __launch_bounds__(256, 2) void k7_gemm(Gemm7 g){
  const int bm = blockIdx.x, bn = blockIdx.y, z = blockIdx.z;
  const u16* W = z ? g.W1 : g.W0;
  const float* bias = z ? g.bias1 : g.bias0;
  const int tbase = z ? g.tb1 : g.tb0;
  u16* outp = g.out + (size_t)z * BATCH * TC * GDIM;
  const int tid = threadIdx.x;
  const int l = tid & 63, l15 = l & 15, lq = l >> 4;
  const int wid = tid >> 6, wm = wid >> 1, wn = wid & 1;

  __shared__ u16 At[2][128 * 40];
  __shared__ u16 Bt[2][128 * 40];

  f32x4 acc[4][4];
#pragma unroll
  for (int i = 0; i < 4; ++i)
#pragma unroll
    for (int j = 0; j < 4; ++j) acc[i][j] = (f32x4){0.f, 0.f, 0.f, 0.f};

  u16x4 alo[2], ahi[2], blo[2], bhi[2];

  auto LOAD = [&](int kt){
#pragma unroll
    for (int c = 0; c < 2; ++c){
      int idx = c * 256 + tid;
      int row = idx >> 2, seg = idx & 3;
      int k0 = kt * 32 + seg * 8;
      int gm = bm * 128 + row;
      size_t arow = (size_t)(gm >> 7) * TSEQ + tbase + (gm & 127);
      if (k0 + 8 <= g.K){
        const u16* p = g.A + arow * g.lda + k0;
        alo[c] = *(const u16x4*)p; ahi[c] = *(const u16x4*)(p + 4);
      } else {
        u16 tmp[8];
#pragma unroll
        for (int e = 0; e < 8; ++e){
          int k = k0 + e;
          tmp[e] = (k < g.K) ? g.A[arow * g.lda + k] : (u16)0;
        }
        alo[c] = (u16x4){tmp[0], tmp[1], tmp[2], tmp[3]};
        ahi[c] = (u16x4){tmp[4], tmp[5], tmp[6], tmp[7]};
      }
      int gn = bn * 128 + row;
      if (k0 + 8 <= g.K){
        const u16* p = W + (size_t)gn * g.ldw + k0;
        blo[c] = *(const u16x4*)p; bhi[c] = *(const u16x4*)(p + 4);
      } else {
        u16 tmp[8];
#pragma unroll
        for (int e = 0; e < 8; ++e){
          int k = k0 + e;
          tmp[e] = (k < g.K) ? W[(size_t)gn * g.ldw + k] : (u16)0;
        }
        blo[c] = (u16x4){tmp[0], tmp[1], tmp[2], tmp[3]};
        bhi[c] = (u16x4){tmp[4], tmp[5], tmp[6], tmp[7]};
      }
    }
  };
  auto STORE = [&](int buf){
#pragma unroll
    for (int c = 0; c < 2; ++c){
      int idx = c * 256 + tid;
      int row = idx >> 2, seg = idx & 3;
      *(u16x4*)&At[buf][row * 40 + seg * 8] = alo[c];
      *(u16x4*)&At[buf][row * 40 + seg * 8 + 4] = ahi[c];
      *(u16x4*)&Bt[buf][row * 40 + seg * 8] = blo[c];
      *(u16x4*)&Bt[buf][row * 40 + seg * 8 + 4] = bhi[c];
    }
  };

  LOAD(0); STORE(0); __syncthreads();
  for (int kt = 0; kt < g.KT; ++kt){
    int cur = kt & 1;
    bool more = (kt + 1 < g.KT);
    if (more) LOAD(kt + 1);
    bf16x8 a[4], b[4];
#pragma unroll
    for (int mi = 0; mi < 4; ++mi)
      a[mi] = *(const bf16x8*)&At[cur][(wm * 64 + mi * 16 + l15) * 40 + lq * 8];
#pragma unroll
    for (int ni = 0; ni < 4; ++ni)
      b[ni] = *(const bf16x8*)&Bt[cur][(wn * 64 + ni * 16 + l15) * 40 + lq * 8];
#pragma unroll
    for (int mi = 0; mi < 4; ++mi)
#pragma unroll
      for (int ni = 0; ni < 4; ++ni)
        acc[mi][ni] = mfma16(a[mi], b[ni], acc[mi][ni]);
    if (more) STORE(cur ^ 1);
    __syncthreads();
  }

#pragma unroll
  for (int mi = 0; mi < 4; ++mi){
#pragma unroll
    for (int ni = 0; ni < 4; ++ni){
      int gn = bn * 128 + wn * 64 + ni * 16 + l15;
      float bs = bias[gn];
#pragma unroll
      for (int r = 0; r < 4; ++r){
        int gm = bm * 128 + wm * 64 + mi * 16 + lq * 4 + r;
        outp[(size_t)gm * GDIM + gn] = f2h16(acc[mi][ni][r] + bs);
      }
    }
  }
}

// ---------------- recurrent LSTM kernel ----------------
// grid 8 = (dir, batch-block of 16). 512 thr = 8 waves. wave w owns gate tiles
// tn16[s], s=0..7. Slots 0,1 held in VGPRs; slots 2..7 streamed via async
// global_load_lds into 3-deep LDS staging, counted vmcnt pipeline.
__global__ __launch_bounds__(512, 2)
void k7_rec(const u16* __restrict__ xgc,   // [2][64][TC][1024] fp16
            const u16* __restrict__ whT,   // layer base: [2 dirs][16 kc][8 w][8 s][512]
            u16* __restrict__ y,           // [64][512][512] bf16
            float* __restrict__ hid,       // [64][512] fp32
            float* __restrict__ stc, float* __restrict__ stef, u16* __restrict__ sth,
            int tb0, int tb1, int first, int write_y, int write_hid)
{
  const int dir = blockIdx.x & 1;
  const int b0  = (blockIdx.x >> 1) << 4;
  const int tid = threadIdx.x;
  const int w   = tid >> 6;
  const int l   = tid & 63;
  const int l15 = l & 15;
  const int lq  = l >> 4;
  const int rev = dir;

  __shared__ u16 hbuf[16 * 256];          // 8KB, xor-swizzled
  __shared__ u16 stg[3][6][8][512];       // 144KB staging (3-deep x 6 slots x 8 waves x 1KB)

  const u16* whd = whT + (size_t)dir * 524288;
  const int qsl = (lq ^ (l15 >> 2)) & 3;
  const int swoff = l15 * 32 + qsl * 8;   // element offset inside a 512-elem chunk
  const int rdoff = swoff * 2;            // byte offset

  int tn16[8];
#pragma unroll
  for (int s = 0; s < 8; ++s) tn16[s] = ((s >> 1) * 16 + 2 * w + (s & 1)) * 16;

  // held slots 0,1 (128 VGPRs)
  bf16x8 held0[16], held1[16];
#pragma unroll
  for (int kc = 0; kc < 16; ++kc){
    held0[kc] = *(const bf16x8*)(whd + (((kc * 8 + w) * 8 + 0) << 9) + swoff);
    held1[kc] = *(const bf16x8*)(whd + (((kc * 8 + w) * 8 + 1) << 9) + swoff);
  }

  int koff[8];
#pragma unroll
  for (int kc = 0; kc < 8; ++kc) koff[kc] = (kc * 64 + lq * 16) ^ ((l15 & 7) << 4);
  const char* hbp = (const char*)hbuf;

  float cst[8], ef[8], hregf[8];
  u16 hreg[8];

  if (first){
    *(f32x4*)((char*)hbuf + tid * 16) = (f32x4){0.f, 0.f, 0.f, 0.f};
#pragma unroll
    for (int i = 0; i < 8; ++i){ cst[i] = 0.f; ef[i] = 0.f; hregf[i] = 0.f; hreg[i] = 0; }
  } else {
#pragma unroll
    for (int th = 0; th < 2; ++th)
#pragma unroll
      for (int r = 0; r < 4; ++r){
        const int idx = th * 4 + r;
        const int m = lq * 4 + r;
        const int j = 32 * w + th * 16 + l15;
        const size_t si = ((size_t)(dir * BATCH + b0 + m)) * HDIM + j;
        cst[idx] = stc[si]; ef[idx] = stef[si];
        u16 hv = sth[si]; hreg[idx] = hv; hregf[idx] = 0.f;
        *(u16*)((char*)hbuf + m * 512 + ((2 * j) ^ ((m & 7) << 4))) = hv;
      }
  }

  size_t xrow[4];
  const int tt0 = rev ? (TC - 1) : 0;
#pragma unroll
  for (int r = 0; r < 4; ++r)
    xrow[r] = ((size_t)dir * BATCH + b0 + lq * 4 + r) * (size_t)(TC * GDIM)
            + (size_t)tt0 * GDIM + l15;
  const long xstep = rev ? -(long)GDIM : (long)GDIM;

#define STAGE(BUF, KC) { \
  _Pragma("unroll") \
  for (int ss = 0; ss < 6; ++ss){ \
    const u16* gp = whd + ((((KC) * 8 + w) * 8 + (ss + 2)) << 9) + l * 8; \
    __builtin_amdgcn_global_load_lds( \
        (const __attribute__((address_space(1))) u32*)gp, \
        (__attribute__((address_space(3))) u32*)&stg[BUF][ss][w][0], 16, 0, 0); \
  } }

#define CONSUME(BUF, KC) { \
  bf16x8 af = *(const bf16x8*)(hbp + l15 * 512 + koff[(KC) & 7]); \
  const char* sb_ = (const char*)&stg[BUF][0][w][0]; \
  bf16x8 w2 = *(const bf16x8*)(sb_ + 0 * 8192 + rdoff); \
  bf16x8 w3 = *(const bf16x8*)(sb_ + 1 * 8192 + rdoff); \
  bf16x8 w4 = *(const bf16x8*)(sb_ + 2 * 8192 + rdoff); \
  bf16x8 w5 = *(const bf16x8*)(sb_ + 3 * 8192 + rdoff); \
  bf16x8 w6 = *(const bf16x8*)(sb_ + 4 * 8192 + rdoff); \
  bf16x8 w7 = *(const bf16x8*)(sb_ + 5 * 8192 + rdoff); \
  acc[0] = mfma16(af, held0[(KC)], acc[0]); \
  acc[1] = mfma16(af, held1[(KC)], acc[1]); \
  acc[2] = mfma16(af, w2, acc[2]); \
  acc[3] = mfma16(af, w3, acc[3]); \
  acc[4] = mfma16(af, w4, acc[4]); \
  acc[5] = mfma16(af, w5, acc[5]); \
  acc[6] = mfma16(af, w6, acc[6]); \
  acc[7] = mfma16(af, w7, acc[7]); }

#define KCI(KC, WN) { \
  asm volatile("s_waitcnt vmcnt(" #WN ")" ::: "memory"); \
  __builtin_amdgcn_sched_barrier(0); \
  CONSUME((KC) % 3, (KC)); \
  if ((KC) + 3 < 16) STAGE((KC) % 3, (KC) + 3); }

#pragma unroll 1
  for (int t = 0; t < TC; ++t){
    const int te = rev ? (tb1 + TC - 1 - t) : (tb0 + t);
    __syncthreads();   // (a) h writes from prev step / init visible

    // xg gate inputs (fp16 scalars; oldest vmem ops this step)
    u16 xgv[8][4];
#pragma unroll
    for (int s = 0; s < 8; ++s)
#pragma unroll
      for (int r = 0; r < 4; ++r) xgv[s][r] = xgc[xrow[r] + tn16[s]];

    f32x4 acc[8];
#pragma unroll
    for (int s = 0; s < 8; ++s) acc[s] = (f32x4){0.f, 0.f, 0.f, 0.f};

    // prologue: stage kc=0,1,2
    STAGE(0, 0) STAGE(1, 1) STAGE(2, 2)

    KCI(0, 12)  KCI(1, 12)  KCI(2, 12)  KCI(3, 12)
    KCI(4, 12)  KCI(5, 12)  KCI(6, 12)  KCI(7, 12)
    KCI(8, 12)  KCI(9, 12)  KCI(10, 12) KCI(11, 12)
    KCI(12, 12) KCI(13, 12) KCI(14, 6)  KCI(15, 0)

    __syncthreads();   // (b) all h reads done before overwriting

#pragma unroll
    for (int th = 0; th < 2; ++th){
#pragma unroll
      for (int r = 0; r < 4; ++r){
        const int idx = th * 4 + r;
        float gi = acc[0 + th][r] + h162f(xgv[0 + th][r]);
        float gf = acc[2 + th][r] + h162f(xgv[2 + th][r]);
        float gg = acc[4 + th][r] + h162f(xgv[4 + th][r]);
        float go = acc[6 + th][r] + h162f(xgv[6 + th][r]);
        float c = sigm(gf) * cst[idx] + sigm(gi) * tanh_(gg);
        cst[idx] = c;
        float h = sigm(go) * tanh_(c);
        hregf[idx] = h;
        float hq = h + ef[idx];
        u16 hb16 = f2b(hq);
        ef[idx] = hq - b2f(hb16);
        hreg[idx] = hb16;
        const int m = lq * 4 + r;
        const int j = 32 * w + th * 16 + l15;
        *(u16*)((char*)hbuf + m * 512 + ((2 * j) ^ ((m & 7) << 4))) = hb16;
        if (write_y)
          y[(((size_t)(b0 + m)) * TSEQ + te) * 512 + dir * 256 + j] = hb16;
      }
    }

#pragma unroll
    for (int r = 0; r < 4; ++r) xrow[r] += xstep;
  }

#undef KCI
#undef CONSUME
#undef STAGE

  // save state / final hidden
#pragma unroll
  for (int th = 0; th < 2; ++th)
#pragma unroll
    for (int r = 0; r < 4; ++r){
      const int idx = th * 4 + r;
      const int m = lq * 4 + r;
      const int j = 32 * w + th * 16 + l15;
      const size_t si = ((size_t)(dir * BATCH + b0 + m)) * HDIM + j;
      stc[si] = cst[idx]; stef[si] = ef[idx]; sth[si] = hreg[idx];
      if (write_hid)
        hid[((size_t)(b0 + m)) * 512 + dir * 256 + j] = hregf[idx];
    }
}

// ---------------- FC in pure fp32 ----------------
__global__ void k7_fc(const float* __restrict__ hid, const float* __restrict__ fcW,
                      const float* __restrict__ fcb, float* __restrict__ out){
  const int b = blockIdx.y;
  const int o = blockIdx.x * 64 + threadIdx.x;
  __shared__ float hs[512];
#pragma unroll
  for (int i = 0; i < 8; ++i) hs[threadIdx.x * 8 + i] = hid[b * 512 + threadIdx.x * 8 + i];
  __syncthreads();
  const f32x4* w4 = (const f32x4*)(fcW + (size_t)o * 512);
  const f32x4* h4 = (const f32x4*)hs;
  float s = 0.f;
#pragma unroll 8
  for (int i = 0; i < 128; ++i){
    f32x4 a = h4[i], bq = w4[i];
    s += a[0] * bq[0] + a[1] * bq[1] + a[2] * bq[2] + a[3] * bq[3];
  }
  out[b * 512 + o] = s + fcb[o];
}

// ---------------- host launch ----------------
extern "C" void kernel_launch(void* const* d_in, const int* in_sizes, int n_in,
                              void* d_out, int out_size, void* d_ws, size_t ws_size,
                              hipStream_t stream)
{
  (void)in_sizes; (void)n_in; (void)out_size; (void)ws_size;
  const int*   text = (const int*)d_in[0];
  const float* emb  = (const float*)d_in[1];
  const float* Wih[4] = {(const float*)d_in[2], (const float*)d_in[6], (const float*)d_in[10], (const float*)d_in[14]};
  const float* Whh[4] = {(const float*)d_in[3], (const float*)d_in[7], (const float*)d_in[11], (const float*)d_in[15]};
  const float* bih[4] = {(const float*)d_in[4], (const float*)d_in[8], (const float*)d_in[12], (const float*)d_in[16]};
  const float* bhh[4] = {(const float*)d_in[5], (const float*)d_in[9], (const float*)d_in[13], (const float*)d_in[17]};
  const float* fcW = (const float*)d_in[18];
  const float* fcb = (const float*)d_in[19];

  char* ws = (char*)d_ws;
  size_t off = 0;
  auto alloc = [&](size_t bytes) -> void* {
    void* p = ws + off;
    off += (bytes + 255) & ~(size_t)255;
    return p;
  };

  u16*   xbf    = (u16*)alloc((size_t)BATCH * TSEQ * ELDA * 2);
  u16*   wihb0f = (u16*)alloc((size_t)GDIM * 300 * 2);
  u16*   wihb0b = (u16*)alloc((size_t)GDIM * 300 * 2);
  u16*   wihb1f = (u16*)alloc((size_t)GDIM * 512 * 2);
  u16*   wihb1b = (u16*)alloc((size_t)GDIM * 512 * 2);
  u16*   whhT   = (u16*)alloc((size_t)4 * 524288 * 2);                 // 4MB transposed hi|lo
  float* bsum   = (float*)alloc((size_t)4 * GDIM * 4);
  u16*   xgc    = (u16*)alloc((size_t)2 * BATCH * TC * GDIM * 2);      // 33.5MB fp16
  u16*   y0     = (u16*)alloc((size_t)BATCH * TSEQ * 512 * 2);         // 33.6MB
  float* stc    = (float*)alloc((size_t)2 * BATCH * HDIM * 4);
  float* stef   = (float*)alloc((size_t)2 * BATCH * HDIM * 4);
  u16*   sth    = (u16*)alloc((size_t)2 * BATCH * HDIM * 2);
  float* hidf   = (float*)alloc((size_t)BATCH * 512 * 4);

  // --- Wih -> bf16 ---
  Cvt7 ca;
  ca.src[0] = Wih[0]; ca.dst[0] = wihb0f;
  ca.src[1] = Wih[1]; ca.dst[1] = wihb0b;
  ca.src[2] = Wih[2]; ca.dst[2] = wihb1f;
  ca.src[3] = Wih[3]; ca.dst[3] = wihb1b;
  {
    int cnt4[4] = {76800, 76800, 131072, 131072};
    ca.cum[0] = 0;
    for (int i = 0; i < 4; ++i) ca.cum[i + 1] = ca.cum[i] + cnt4[i];
  }
  k7_cvt<<<dim3((415744 + 255) / 256), dim3(256), 0, stream>>>(ca);

  // --- Whh -> transposed swizzled hi|lo chunks ---
  CvtW7 cw;
  for (int k = 0; k < 4; ++k) cw.src[k] = Whh[k];
  cw.dst = whhT;
  k7_cvtw<<<dim3(1024), dim3(256), 0, stream>>>(cw);

  Bias7 ba;
  for (int k = 0; k < 4; ++k){ ba.a[k] = bih[k]; ba.b[k] = bhh[k]; ba.d[k] = bsum + k * GDIM; }
  k7_bias<<<dim3(4), dim3(1024), 0, stream>>>(ba);

  k7_embed<<<dim3(BATCH * TSEQ), dim3(128), 0, stream>>>(text, emb, xbf);

  // --- layer 0: chunked gemm + recurrence ---
  for (int c = 0; c < NC; ++c){
    Gemm7 g0;
    g0.A = xbf; g0.lda = ELDA; g0.K = 300; g0.KT = 10;
    g0.W0 = wihb0f; g0.W1 = wihb0b; g0.ldw = 300;
    g0.bias0 = bsum; g0.bias1 = bsum + GDIM;
    g0.out = xgc; g0.tb0 = c * TC; g0.tb1 = (TSEQ - TC) - c * TC;
    k7_gemm<<<dim3(64, 8, 2), dim3(256), 0, stream>>>(g0);
    k7_rec<<<dim3(8), dim3(512), 0, stream>>>(xgc, whhT, y0, hidf,
        stc, stef, sth, c * TC, (TSEQ - TC) - c * TC, (c == 0) ? 1 : 0, 1, 0);
  }

  // --- layer 1: chunked gemm + recurrence ---
  for (int c = 0; c < NC; ++c){
    Gemm7 g1;
    g1.A = y0; g1.lda = 512; g1.K = 512; g1.KT = 16;
    g1.W0 = wihb1f; g1.W1 = wihb1b; g1.ldw = 512;
    g1.bias0 = bsum + 2 * GDIM; g1.bias1 = bsum + 3 * GDIM;
    g1.out = xgc; g1.tb0 = c * TC; g1.tb1 = (TSEQ - TC) - c * TC;
    k7_gemm<<<dim3(64, 8, 2), dim3(256), 0, stream>>>(g1);
    k7_rec<<<dim3(8), dim3(512), 0, stream>>>(xgc, whhT + (size_t)2 * 524288, y0, hidf,
        stc, stef, sth, c * TC, (TSEQ - TC) - c * TC, (c == 0) ? 1 : 0, 0, (c == NC - 1) ? 1 : 0);
  }

  // --- FC in fp32 from fp32 weights ---
  k7_fc<<<dim3(8, 64), dim3(64), 0, stream>>>(hidf, fcW, fcb, (float*)d_out);
}